// Round 1
// 1240.033 us; speedup vs baseline: 1.0099x; 1.0099x over previous
//
#include <hip/hip_runtime.h>
#include <hip/hip_bf16.h>

// ---------------- problem constants ----------------
#define H_DIM 256
#define O_DIM 128
#define NEXP 4
#define G_DIM 64

typedef unsigned short ushort_t;
typedef unsigned int uint_t;
typedef __attribute__((ext_vector_type(8))) short short8;
typedef __attribute__((ext_vector_type(4))) float floatx4;

// ---------------- bf16 helpers (RNE) ----------------
__device__ __forceinline__ float bf2f(ushort_t u) {
    union { uint_t i; float f; } c; c.i = ((uint_t)u) << 16; return c.f;
}
__device__ __forceinline__ ushort_t f2bf(float f) {
    union { float f; uint_t i; } c; c.f = f;
    uint_t x = c.i;
    uint_t r = (x + 0x7fffu + ((x >> 16) & 1u)) >> 16;
    return (ushort_t)r;
}

// ---------------- async global->LDS 16B ----------------
__device__ __forceinline__ void load16_lds(const void* g, void* l) {
    __builtin_amdgcn_global_load_lds(
        (const __attribute__((address_space(1))) unsigned int*)g,
        (__attribute__((address_space(3))) unsigned int*)l, 16, 0, 0);
}

// ---------------- utility: zero ints ----------------
__global__ void zero_i_kernel(int* __restrict__ p, long n) {
    long i = (long)blockIdx.x * blockDim.x + threadIdx.x;
    if (i < n) p[i] = 0;
}

// ---------------- fused weight prep (single bf16, transposed) ----------------
__global__ void wsplit2_kernel(const float* __restrict__ Wa, const float* __restrict__ Wb,
                               ushort_t* __restrict__ Wh) {
    int z = blockIdx.y;
    int i = blockIdx.x * 256 + threadIdx.x;        // 256n * 512k
    if (i >= 131072) return;
    int nn = i >> 9, kk = i & 511;
    float v = (kk < 256) ? Wa[(long)z * 65536 + kk * 256 + nn]
                         : Wb[(long)z * 65536 + (kk - 256) * 256 + nn];
    Wh[(long)z * 131072 + i] = f2bf(v);
}

__global__ void wsplitcat_kernel(const float* __restrict__ Wa, const float* __restrict__ Wb,
                                 ushort_t* __restrict__ Wh) {
    int z = blockIdx.y;
    int i = blockIdx.x * 256 + threadIdx.x;        // 256n * 256k
    if (i >= 65536) return;
    int nn = i >> 8, kk = i & 255;
    float v = (nn < 128) ? Wa[(long)z * 32768 + kk * 128 + nn]
                         : Wb[(long)z * 32768 + kk * 128 + (nn - 128)];
    Wh[(long)z * 65536 + i] = f2bf(v);
}

// ---------------- encoder stage 1 (fp32, verified) ----------------
__global__ void encoder1_kernel(const float* __restrict__ x, const float* __restrict__ W1,
                                const float* __restrict__ b1, float* __restrict__ u,
                                int N, int F) {
    int n = blockIdx.x;
    int j = threadIdx.x;
    float acc = b1[j];
    #pragma unroll
    for (int c = 0; c < 6; ++c)
        acc += x[(long)n * F + 4 + c] * W1[c * H_DIM + j];
    u[(long)n * H_DIM + j] = fmaxf(acc, 0.f);
}

// ---------------- fp32 vector SGEMM (router path — DO NOT CHANGE: top-2 flip risk) ----------------
__global__ __launch_bounds__(256)
void gemm256_kernel(const float* __restrict__ A, const float* __restrict__ W,
                    const float* __restrict__ bias, float* __restrict__ C,
                    ushort_t* __restrict__ Cbf, int M, int Nc) {
    const int K = 256;
    __shared__ float As[16][68];
    __shared__ float Ws[16][68];
    int tid = threadIdx.x;
    int tx = tid & 15, ty = tid >> 4;
    int row0 = blockIdx.x * 64;
    int col0 = blockIdx.y * 64;
    float acc[4][4] = {};
    int lrow = tid >> 2, kq = tid & 3;
    int wk = tid >> 4, wc = (tid & 15) * 4;
    for (int k0 = 0; k0 < K; k0 += 16) {
        float4 av = make_float4(0.f, 0.f, 0.f, 0.f);
        int arow = row0 + lrow;
        if (arow < M) av = *(const float4*)(A + (long)arow * K + k0 + kq * 4);
        As[kq * 4 + 0][lrow] = av.x;
        As[kq * 4 + 1][lrow] = av.y;
        As[kq * 4 + 2][lrow] = av.z;
        As[kq * 4 + 3][lrow] = av.w;
        float4 wv = *(const float4*)(W + (long)(k0 + wk) * Nc + col0 + wc);
        *(float4*)&Ws[wk][wc] = wv;
        __syncthreads();
        #pragma unroll
        for (int kk = 0; kk < 16; ++kk) {
            float a[4], b[4];
            #pragma unroll
            for (int i = 0; i < 4; ++i) a[i] = As[kk][ty * 4 + i];
            #pragma unroll
            for (int j = 0; j < 4; ++j) b[j] = Ws[kk][tx * 4 + j];
            #pragma unroll
            for (int i = 0; i < 4; ++i)
                #pragma unroll
                for (int j = 0; j < 4; ++j) acc[i][j] += a[i] * b[j];
        }
        __syncthreads();
    }
    #pragma unroll
    for (int i = 0; i < 4; ++i) {
        int r = row0 + ty * 4 + i;
        if (r >= M) break;
        #pragma unroll
        for (int j = 0; j < 4; ++j) {
            int c = col0 + tx * 4 + j;
            float v = acc[i][j];
            if (bias) v += bias[c];
            C[(long)r * Nc + c] = v;
            if (Cbf) Cbf[(long)r * Nc + c] = f2bf(v);
        }
    }
}

// ---------------- bf16 MFMA GEMM, 64x128 tile, double-buffered, z-batched ----------------
// C[z] = [relu]( sum_halves A_half[z](bf16) @ B[z]^T + [bias[z]] ); B fused (Nc=256, Kb) bf16.
// 64x128 tile, BK=32, 4 waves (2x2, wave tile 32x64), 2x4 frags of 16x16x32.
// LDS 24 KB -> ~6 resident blocks/CU; grid 2x vs 128-tile -> latency hidden by TLP.
// Add-rotate LDS swizzle (modulo-4 algebra verified R6-R10).
template<int NH>
__global__ __launch_bounds__(256)
void gemm_bf_kernel(const ushort_t* __restrict__ A1, long sA1z, int rsA1,
                    const ushort_t* __restrict__ A2, long sA2z, int rsA2,
                    const ushort_t* __restrict__ B, long sBz,
                    const float* __restrict__ bias, int sBiasz,
                    ushort_t* __restrict__ Cbf, long sCz, int rsC,
                    int M, int Kb, int relu) {
    __shared__ alignas(16) ushort_t Asl[2][64 * 32];
    __shared__ alignas(16) ushort_t Bsl[2][128 * 32];

    const int tid = threadIdx.x, wave = tid >> 6, lane = tid & 63;
    const int z = blockIdx.z;
    const int row0 = blockIdx.x * 64, col0 = blockIdx.y * 128;
    const int wr = (wave >> 1) * 32, wcx = (wave & 1) * 64;
    floatx4 acc[2][4] = {};

    A1 += (long)z * sA1z;
    A2 += (long)z * sA2z;
    B += (long)z * sBz;
    if (bias) bias += (long)z * sBiasz;
    Cbf += (long)z * sCz;

    // staging map: 4 lanes/row (4x16B chunks), add-rotate swizzle
    const int bsr = lane >> 2;                    // row in group of 16
    const int bgc = ((lane & 3) - (bsr >> 1)) & 3;
    long aoff1, aoff2;
    {
        int ar = row0 + wave * 16 + bsr;          // A: 16 rows per wave
        ar = ar < M ? ar : M - 1;
        aoff1 = (long)ar * rsA1 + bgc * 8;
        aoff2 = (long)ar * rsA2 + bgc * 8;
    }
    const long brow = (long)(col0 + wave * 32 + bsr) * Kb + bgc * 8;
    const ushort_t* Bg0 = B + brow;
    const ushort_t* Bg1 = B + brow + (long)16 * Kb;
    const int laA  = (wave * 16) * 32;
    const int laB0 = (wave * 32) * 32;
    const int laB1 = (wave * 32 + 16) * 32;

    const int fm = lane & 15, fq = lane >> 4;
    const int NK = NH * 8;

    // stage k=0 into buffer 0
    load16_lds(A1 + aoff1, &Asl[0][laA]);
    load16_lds(Bg0, &Bsl[0][laB0]);
    load16_lds(Bg1, &Bsl[0][laB1]);
    __syncthreads();

    for (int k = 0; k < NK; ++k) {
        const int buf = k & 1;
        short8 a[2], b[4];
        #pragma unroll
        for (int j = 0; j < 4; ++j) {
            int row = wcx + j * 16 + fm;
            int slot = (fq + ((row >> 1) & 3)) & 3;
            b[j] = *(const short8*)&Bsl[buf][row * 32 + slot * 8];
        }
        #pragma unroll
        for (int i = 0; i < 2; ++i) {
            int row = wr + i * 16 + fm;
            int slot = (fq + ((row >> 1) & 3)) & 3;
            a[i] = *(const short8*)&Asl[buf][row * 32 + slot * 8];
        }
        if (k + 1 < NK) {
            const int kn = k + 1, bn = kn & 1;
            const ushort_t* Ab = (kn >> 3) ? A2 : A1;
            const long ao = (kn >> 3) ? aoff2 : aoff1;
            const int k0 = (kn & 7) * 32;          // within-half A offset
            const int kk = kn * 32;                // fused-K B offset
            load16_lds(Ab + ao + k0, &Asl[bn][laA]);
            load16_lds(Bg0 + kk, &Bsl[bn][laB0]);
            load16_lds(Bg1 + kk, &Bsl[bn][laB1]);
        }
        #pragma unroll
        for (int i = 0; i < 2; ++i)
            #pragma unroll
            for (int j = 0; j < 4; ++j)
                acc[i][j] = __builtin_amdgcn_mfma_f32_16x16x32_bf16(a[i], b[j], acc[i][j], 0, 0, 0);
        if (k + 1 < NK) __syncthreads();
    }

    // epilogue: C/D layout col=lane&15, row=(lane>>4)*4+reg  [verified m89]
    #pragma unroll
    for (int i = 0; i < 2; ++i) {
        #pragma unroll
        for (int j = 0; j < 4; ++j) {
            int col = col0 + wcx + j * 16 + fm;
            int rowb = row0 + wr + i * 16 + fq * 4;
            #pragma unroll
            for (int r = 0; r < 4; ++r) {
                int row = rowb + r;
                if (row < M) {
                    float v = acc[i][j][r];
                    if (bias) v += bias[col];
                    if (relu) v = fmaxf(v, 0.f);
                    Cbf[(long)row * rsC + col] = f2bf(v);
                }
            }
        }
    }
}

// ---------------- graph-stat histograms ----------------
__global__ void hist_nodes_kernel(const int* __restrict__ batch, int n, int* __restrict__ gn) {
    __shared__ int bins[G_DIM];
    int t = threadIdx.x;
    if (t < G_DIM) bins[t] = 0;
    __syncthreads();
    for (long i = (long)blockIdx.x * blockDim.x + t; i < n; i += (long)gridDim.x * blockDim.x)
        atomicAdd(&bins[batch[i]], 1);
    __syncthreads();
    if (t < G_DIM) atomicAdd(&gn[t], bins[t]);
}

__global__ void hist_edges_kernel(const int* __restrict__ ei, const int* __restrict__ batch,
                                  int E, int* __restrict__ ge) {
    __shared__ int bins[G_DIM];
    int t = threadIdx.x;
    if (t < G_DIM) bins[t] = 0;
    __syncthreads();
    for (long i = (long)blockIdx.x * blockDim.x + t; i < E; i += (long)gridDim.x * blockDim.x)
        atomicAdd(&bins[batch[ei[i]]], 1);
    __syncthreads();
    if (t < G_DIM) atomicAdd(&ge[t], bins[t]);
}

// ---------------- graph stats ----------------
__global__ void graph_stats_kernel(const int* __restrict__ gn, const int* __restrict__ ge,
                                   float* __restrict__ feats_norm, float* __restrict__ logn_norm) {
    int g = threadIdx.x;
    float nv = fmaxf((float)gn[g], 1.0f);
    float ev = (float)ge[g];
    float density = ev / fmaxf(nv * (nv - 1.0f), 1.0f);
    float logn = logf(nv);
    float mn = logn, mx = logn;
    for (int o = 32; o; o >>= 1) {
        mn = fminf(mn, __shfl_xor(mn, o));
        mx = fmaxf(mx, __shfl_xor(mx, o));
    }
    logn_norm[g] = (logn - mn) / (mx - mn + 1e-6f);
    float f[3] = {nv, ev, density};
    #pragma unroll
    for (int c = 0; c < 3; ++c) {
        float s = f[c];
        for (int o = 32; o; o >>= 1) s += __shfl_xor(s, o);
        float mean = s / 64.f;
        float d = f[c] - mean;
        float v = d * d;
        for (int o = 32; o; o >>= 1) v += __shfl_xor(v, o);
        float stdv = sqrtf(v / 64.f);
        feats_norm[g * 3 + c] = d / (stdv + 1e-6f);
    }
}

// ---------------- router epilogue (verified) ----------------
__global__ __launch_bounds__(256)
void router_epi_kernel(const float* __restrict__ t, const int* __restrict__ batch,
                       const float* __restrict__ feats_norm, const float* __restrict__ logn_norm,
                       const float* __restrict__ rW1, const float* __restrict__ rb1,
                       const float* __restrict__ lng, const float* __restrict__ lnb,
                       const float* __restrict__ rW2, const float* __restrict__ rb2,
                       const float* __restrict__ centers, float* __restrict__ w, int N) {
    int wave = threadIdx.x >> 6, lane = threadIdx.x & 63;
    int n = blockIdx.x * 4 + wave;
    if (n >= N) return;
    int g = batch[n];
    float sf0 = feats_norm[g * 3 + 0], sf1 = feats_norm[g * 3 + 1], sf2 = feats_norm[g * 3 + 2];
    float ln = logn_norm[g];
    float tv[4];
    #pragma unroll
    for (int q = 0; q < 4; ++q) {
        int j = lane + 64 * q;
        tv[q] = t[(long)n * H_DIM + j] + rb1[j]
              + sf0 * rW1[256 * H_DIM + j] + sf1 * rW1[257 * H_DIM + j] + sf2 * rW1[258 * H_DIM + j];
    }
    float s = tv[0] + tv[1] + tv[2] + tv[3];
    for (int o = 32; o; o >>= 1) s += __shfl_xor(s, o);
    float mean = s / 256.f;
    float vs = 0.f;
    #pragma unroll
    for (int q = 0; q < 4; ++q) { float d = tv[q] - mean; vs += d * d; }
    for (int o = 32; o; o >>= 1) vs += __shfl_xor(vs, o);
    float rstd = rsqrtf(vs / 256.f + 1e-5f);
    float le[NEXP] = {0.f, 0.f, 0.f, 0.f};
    #pragma unroll
    for (int q = 0; q < 4; ++q) {
        int j = lane + 64 * q;
        float y = (tv[q] - mean) * rstd * lng[j] + lnb[j];
        y = fmaxf(y, 0.f);
        #pragma unroll
        for (int e = 0; e < NEXP; ++e) le[e] += y * rW2[j * NEXP + e];
    }
    #pragma unroll
    for (int e = 0; e < NEXP; ++e)
        for (int o = 32; o; o >>= 1) le[e] += __shfl_xor(le[e], o);
    if (lane == 0) {
        float p[NEXP];
        float m = -1e30f;
        #pragma unroll
        for (int e = 0; e < NEXP; ++e) {
            float d = ln - centers[e];
            float lv = 0.7f * (le[e] + rb2[e]) + 0.3f * (-(d * d));
            p[e] = lv;
            m = fmaxf(m, lv);
        }
        float ssum = 0.f;
        #pragma unroll
        for (int e = 0; e < NEXP; ++e) { p[e] = expf(p[e] - m); ssum += p[e]; }
        #pragma unroll
        for (int e = 0; e < NEXP; ++e) p[e] /= ssum;
        int i1 = 0;
        for (int e = 1; e < NEXP; ++e) if (p[e] > p[i1]) i1 = e;
        int i2 = -1;
        for (int e = 0; e < NEXP; ++e) { if (e == i1) continue; if (i2 < 0 || p[e] > p[i2]) i2 = e; }
        float denom = p[i1] + p[i2] + 1e-8f;
        float out4[NEXP] = {0.f, 0.f, 0.f, 0.f};
        out4[i1] = p[i1] / denom;
        out4[i2] = p[i2] / denom;
        #pragma unroll
        for (int e = 0; e < NEXP; ++e) w[(long)n * NEXP + e] = out4[e];
    }
}

// ---------------- CSR build ----------------
__global__ void count_dst_kernel(const int* __restrict__ ei, int E, int* __restrict__ cnt) {
    int i = blockIdx.x * blockDim.x + threadIdx.x;
    if (i < E) atomicAdd(&cnt[ei[E + i]], 1);
}

__global__ __launch_bounds__(1024)
void scan_kernel(const int* __restrict__ cnt, int* __restrict__ row_ptr, int n) {
    __shared__ int buf[1024];
    __shared__ int carry_s;
    int tid = threadIdx.x;
    if (tid == 0) carry_s = 0;
    __syncthreads();
    for (int base = 0; base < n; base += 1024) {
        int v = (base + tid < n) ? cnt[base + tid] : 0;
        buf[tid] = v;
        __syncthreads();
        for (int off = 1; off < 1024; off <<= 1) {
            int tv = (tid >= off) ? buf[tid - off] : 0;
            __syncthreads();
            buf[tid] += tv;
            __syncthreads();
        }
        int carry = carry_s;
        if (base + tid < n) row_ptr[base + tid] = carry + buf[tid] - v;
        __syncthreads();
        if (tid == 1023) carry_s = carry + buf[1023];
        __syncthreads();
    }
    if (tid == 0) row_ptr[n] = carry_s;
}

__global__ void fill_csr_kernel(const int* __restrict__ ei, int E, const int* __restrict__ row_ptr,
                                int* __restrict__ fillc, int* __restrict__ srcs) {
    int i = blockIdx.x * blockDim.x + threadIdx.x;
    if (i < E) {
        int d = ei[E + i];
        int pos = row_ptr[d] + atomicAdd(&fillc[d], 1);
        srcs[pos] = ei[i];
    }
}

// ---------------- flat CSR gather bf16 (agg_h), wave/node, edge-unrolled x8 ----------------
// Accumulation written as two sequential x4 groups -> bit-identical fp32 order to the
// verified x4 kernel; only load issue depth changes (latency hiding, R0->R1).
__global__ __launch_bounds__(256)
void agg_b2b_kernel(const ushort_t* __restrict__ feat, ushort_t* __restrict__ outp,
                    const int* __restrict__ rp, const int* __restrict__ srcs, int N) {
    int wave = threadIdx.x >> 6, lane = threadIdx.x & 63;
    int n = blockIdx.x * 4 + wave;
    if (n >= N) return;
    float a0 = 0.f, a1 = 0.f, a2 = 0.f, a3 = 0.f;
    int p0 = rp[n], p1 = rp[n + 1];
    const ushort_t* base = feat + lane * 4;
    int p = p0;
    for (; p + 7 < p1; p += 8) {
        uint2 v0 = *(const uint2*)(base + (long)srcs[p] * H_DIM);
        uint2 v1 = *(const uint2*)(base + (long)srcs[p + 1] * H_DIM);
        uint2 v2 = *(const uint2*)(base + (long)srcs[p + 2] * H_DIM);
        uint2 v3 = *(const uint2*)(base + (long)srcs[p + 3] * H_DIM);
        uint2 v4 = *(const uint2*)(base + (long)srcs[p + 4] * H_DIM);
        uint2 v5 = *(const uint2*)(base + (long)srcs[p + 5] * H_DIM);
        uint2 v6 = *(const uint2*)(base + (long)srcs[p + 6] * H_DIM);
        uint2 v7 = *(const uint2*)(base + (long)srcs[p + 7] * H_DIM);
        // group 1 (edges 0-3) — same add order as verified x4 body
        a0 += bf2f((ushort_t)(v0.x & 0xffff)) + bf2f((ushort_t)(v1.x & 0xffff))
            + bf2f((ushort_t)(v2.x & 0xffff)) + bf2f((ushort_t)(v3.x & 0xffff));
        a1 += bf2f((ushort_t)(v0.x >> 16)) + bf2f((ushort_t)(v1.x >> 16))
            + bf2f((ushort_t)(v2.x >> 16)) + bf2f((ushort_t)(v3.x >> 16));
        a2 += bf2f((ushort_t)(v0.y & 0xffff)) + bf2f((ushort_t)(v1.y & 0xffff))
            + bf2f((ushort_t)(v2.y & 0xffff)) + bf2f((ushort_t)(v3.y & 0xffff));
        a3 += bf2f((ushort_t)(v0.y >> 16)) + bf2f((ushort_t)(v1.y >> 16))
            + bf2f((ushort_t)(v2.y >> 16)) + bf2f((ushort_t)(v3.y >> 16));
        // group 2 (edges 4-7)
        a0 += bf2f((ushort_t)(v4.x & 0xffff)) + bf2f((ushort_t)(v5.x & 0xffff))
            + bf2f((ushort_t)(v6.x & 0xffff)) + bf2f((ushort_t)(v7.x & 0xffff));
        a1 += bf2f((ushort_t)(v4.x >> 16)) + bf2f((ushort_t)(v5.x >> 16))
            + bf2f((ushort_t)(v6.x >> 16)) + bf2f((ushort_t)(v7.x >> 16));
        a2 += bf2f((ushort_t)(v4.y & 0xffff)) + bf2f((ushort_t)(v5.y & 0xffff))
            + bf2f((ushort_t)(v6.y & 0xffff)) + bf2f((ushort_t)(v7.y & 0xffff));
        a3 += bf2f((ushort_t)(v4.y >> 16)) + bf2f((ushort_t)(v5.y >> 16))
            + bf2f((ushort_t)(v6.y >> 16)) + bf2f((ushort_t)(v7.y >> 16));
    }
    for (; p + 3 < p1; p += 4) {
        uint2 v0 = *(const uint2*)(base + (long)srcs[p] * H_DIM);
        uint2 v1 = *(const uint2*)(base + (long)srcs[p + 1] * H_DIM);
        uint2 v2 = *(const uint2*)(base + (long)srcs[p + 2] * H_DIM);
        uint2 v3 = *(const uint2*)(base + (long)srcs[p + 3] * H_DIM);
        a0 += bf2f((ushort_t)(v0.x & 0xffff)) + bf2f((ushort_t)(v1.x & 0xffff))
            + bf2f((ushort_t)(v2.x & 0xffff)) + bf2f((ushort_t)(v3.x & 0xffff));
        a1 += bf2f((ushort_t)(v0.x >> 16)) + bf2f((ushort_t)(v1.x >> 16))
            + bf2f((ushort_t)(v2.x >> 16)) + bf2f((ushort_t)(v3.x >> 16));
        a2 += bf2f((ushort_t)(v0.y & 0xffff)) + bf2f((ushort_t)(v1.y & 0xffff))
            + bf2f((ushort_t)(v2.y & 0xffff)) + bf2f((ushort_t)(v3.y & 0xffff));
        a3 += bf2f((ushort_t)(v0.y >> 16)) + bf2f((ushort_t)(v1.y >> 16))
            + bf2f((ushort_t)(v2.y >> 16)) + bf2f((ushort_t)(v3.y >> 16));
    }
    for (; p < p1; ++p) {
        uint2 v = *(const uint2*)(base + (long)srcs[p] * H_DIM);
        a0 += bf2f((ushort_t)(v.x & 0xffff));
        a1 += bf2f((ushort_t)(v.x >> 16));
        a2 += bf2f((ushort_t)(v.y & 0xffff));
        a3 += bf2f((ushort_t)(v.y >> 16));
    }
    uint2 o;
    o.x = (uint_t)f2bf(a0) | ((uint_t)f2bf(a1) << 16);
    o.y = (uint_t)f2bf(a2) | ((uint_t)f2bf(a3) << 16);
    *(uint2*)(outp + (long)n * H_DIM + lane * 4) = o;
}

// ---------------- interleaved CSR gather, 16B/lane: feat [n][W] bf16; block = W/8 threads ----------------
// Edge-unrolled x8 as two sequential x4 groups (bit-identical fp32 order to verified x4).
__global__ void aggI_kernel(const ushort_t* __restrict__ feat, ushort_t* __restrict__ outp,
                            const int* __restrict__ rp, const int* __restrict__ srcs,
                            int N, int W) {
    int n = blockIdx.x;
    int t = threadIdx.x;                      // t < W/8, 8 bf16 per thread
    float a[8] = {0.f, 0.f, 0.f, 0.f, 0.f, 0.f, 0.f, 0.f};
    int p0 = rp[n], p1 = rp[n + 1];
    const ushort_t* base = feat + t * 8;
    int p = p0;
    for (; p + 7 < p1; p += 8) {
        uint4 v0 = *(const uint4*)(base + (long)srcs[p] * W);
        uint4 v1 = *(const uint4*)(base + (long)srcs[p + 1] * W);
        uint4 v2 = *(const uint4*)(base + (long)srcs[p + 2] * W);
        uint4 v3 = *(const uint4*)(base + (long)srcs[p + 3] * W);
        uint4 v4 = *(const uint4*)(base + (long)srcs[p + 4] * W);
        uint4 v5 = *(const uint4*)(base + (long)srcs[p + 5] * W);
        uint4 v6 = *(const uint4*)(base + (long)srcs[p + 6] * W);
        uint4 v7 = *(const uint4*)(base + (long)srcs[p + 7] * W);
        {
            uint_t w0[4] = {v0.x, v0.y, v0.z, v0.w};
            uint_t w1[4] = {v1.x, v1.y, v1.z, v1.w};
            uint_t w2[4] = {v2.x, v2.y, v2.z, v2.w};
            uint_t w3[4] = {v3.x, v3.y, v3.z, v3.w};
            #pragma unroll
            for (int q = 0; q < 4; ++q) {
                a[2 * q]     += bf2f((ushort_t)(w0[q] & 0xffff)) + bf2f((ushort_t)(w1[q] & 0xffff))
                              + bf2f((ushort_t)(w2[q] & 0xffff)) + bf2f((ushort_t)(w3[q] & 0xffff));
                a[2 * q + 1] += bf2f((ushort_t)(w0[q] >> 16)) + bf2f((ushort_t)(w1[q] >> 16))
                              + bf2f((ushort_t)(w2[q] >> 16)) + bf2f((ushort_t)(w3[q] >> 16));
            }
        }
        {
            uint_t w0[4] = {v4.x, v4.y, v4.z, v4.w};
            uint_t w1[4] = {v5.x, v5.y, v5.z, v5.w};
            uint_t w2[4] = {v6.x, v6.y, v6.z, v6.w};
            uint_t w3[4] = {v7.x, v7.y, v7.z, v7.w};
            #pragma unroll
            for (int q = 0; q < 4; ++q) {
                a[2 * q]     += bf2f((ushort_t)(w0[q] & 0xffff)) + bf2f((ushort_t)(w1[q] & 0xffff))
                              + bf2f((ushort_t)(w2[q] & 0xffff)) + bf2f((ushort_t)(w3[q] & 0xffff));
                a[2 * q + 1] += bf2f((ushort_t)(w0[q] >> 16)) + bf2f((ushort_t)(w1[q] >> 16))
                              + bf2f((ushort_t)(w2[q] >> 16)) + bf2f((ushort_t)(w3[q] >> 16));
            }
        }
    }
    for (; p + 3 < p1; p += 4) {
        uint4 v0 = *(const uint4*)(base + (long)srcs[p] * W);
        uint4 v1 = *(const uint4*)(base + (long)srcs[p + 1] * W);
        uint4 v2 = *(const uint4*)(base + (long)srcs[p + 2] * W);
        uint4 v3 = *(const uint4*)(base + (long)srcs[p + 3] * W);
        uint_t w0[4] = {v0.x, v0.y, v0.z, v0.w};
        uint_t w1[4] = {v1.x, v1.y, v1.z, v1.w};
        uint_t w2[4] = {v2.x, v2.y, v2.z, v2.w};
        uint_t w3[4] = {v3.x, v3.y, v3.z, v3.w};
        #pragma unroll
        for (int q = 0; q < 4; ++q) {
            a[2 * q]     += bf2f((ushort_t)(w0[q] & 0xffff)) + bf2f((ushort_t)(w1[q] & 0xffff))
                          + bf2f((ushort_t)(w2[q] & 0xffff)) + bf2f((ushort_t)(w3[q] & 0xffff));
            a[2 * q + 1] += bf2f((ushort_t)(w0[q] >> 16)) + bf2f((ushort_t)(w1[q] >> 16))
                          + bf2f((ushort_t)(w2[q] >> 16)) + bf2f((ushort_t)(w3[q] >> 16));
        }
    }
    for (; p < p1; ++p) {
        uint4 v = *(const uint4*)(base + (long)srcs[p] * W);
        uint_t w[4] = {v.x, v.y, v.z, v.w};
        #pragma unroll
        for (int q = 0; q < 4; ++q) {
            a[2 * q]     += bf2f((ushort_t)(w[q] & 0xffff));
            a[2 * q + 1] += bf2f((ushort_t)(w[q] >> 16));
        }
    }
    uint4 o;
    o.x = (uint_t)f2bf(a[0]) | ((uint_t)f2bf(a[1]) << 16);
    o.y = (uint_t)f2bf(a[2]) | ((uint_t)f2bf(a[3]) << 16);
    o.z = (uint_t)f2bf(a[4]) | ((uint_t)f2bf(a[5]) << 16);
    o.w = (uint_t)f2bf(a[6]) | ((uint_t)f2bf(a[7]) << 16);
    *(uint4*)(outp + (long)n * W + t * 8) = o;
}

// ---------------- final mix on interleaved PR rows [n][z][256] (P cols 0..127, R 128..255) ----------------
// na==2 path unrolled x4 (two sequential x2 groups), na==1 path unrolled x8 (two x4 groups);
// fp32 add order bit-identical to the verified kernel.
__global__ __launch_bounds__(256)
void final_mixE_kernel(const ushort_t* __restrict__ PR, const float* __restrict__ b2,
                       const float* __restrict__ wts, int e0, int EB,
                       const int* __restrict__ rp, const int* __restrict__ srcs,
                       float* __restrict__ out, int N, int init) {
    int wave = threadIdx.x >> 6, lane = threadIdx.x & 63;
    int n = blockIdx.x * 4 + wave;
    if (n >= N) return;
    const int W = EB * 256;
    int c0 = lane * 2;
    long obase = (long)n * O_DIM + c0;
    float o0 = init ? 0.f : out[obase];
    float o1 = init ? 0.f : out[obase + 1];
    int zs[2]; float wv[2]; int na = 0;
    for (int z = 0; z < EB; ++z) {
        float w = wts[(long)n * NEXP + e0 + z];
        if (w != 0.f && na < 2) { zs[na] = z; wv[na] = w; ++na; }
    }
    if (na) {
        const ushort_t* P0 = PR + zs[0] * 256 + c0;
        const ushort_t* P1 = PR + zs[na - 1] * 256 + c0;
        float a00 = 0.f, a01 = 0.f, a10 = 0.f, a11 = 0.f;
        int p0 = rp[n], p1 = rp[n + 1];
        if (na == 2) {
            int p = p0;
            for (; p + 3 < p1; p += 4) {
                long s0 = (long)srcs[p] * W;
                long s1 = (long)srcs[p + 1] * W;
                long s2 = (long)srcs[p + 2] * W;
                long s3 = (long)srcs[p + 3] * W;
                uint_t v00 = *(const uint_t*)(P0 + s0);
                uint_t v10 = *(const uint_t*)(P1 + s0);
                uint_t v01 = *(const uint_t*)(P0 + s1);
                uint_t v11 = *(const uint_t*)(P1 + s1);
                uint_t v02 = *(const uint_t*)(P0 + s2);
                uint_t v12 = *(const uint_t*)(P1 + s2);
                uint_t v03 = *(const uint_t*)(P0 + s3);
                uint_t v13 = *(const uint_t*)(P1 + s3);
                a00 += bf2f((ushort_t)(v00 & 0xffff)) + bf2f((ushort_t)(v01 & 0xffff));
                a01 += bf2f((ushort_t)(v00 >> 16))    + bf2f((ushort_t)(v01 >> 16));
                a10 += bf2f((ushort_t)(v10 & 0xffff)) + bf2f((ushort_t)(v11 & 0xffff));
                a11 += bf2f((ushort_t)(v10 >> 16))    + bf2f((ushort_t)(v11 >> 16));
                a00 += bf2f((ushort_t)(v02 & 0xffff)) + bf2f((ushort_t)(v03 & 0xffff));
                a01 += bf2f((ushort_t)(v02 >> 16))    + bf2f((ushort_t)(v03 >> 16));
                a10 += bf2f((ushort_t)(v12 & 0xffff)) + bf2f((ushort_t)(v13 & 0xffff));
                a11 += bf2f((ushort_t)(v12 >> 16))    + bf2f((ushort_t)(v13 >> 16));
            }
            for (; p + 1 < p1; p += 2) {
                long s0 = (long)srcs[p] * W;
                long s1 = (long)srcs[p + 1] * W;
                uint_t v00 = *(const uint_t*)(P0 + s0);
                uint_t v10 = *(const uint_t*)(P1 + s0);
                uint_t v01 = *(const uint_t*)(P0 + s1);
                uint_t v11 = *(const uint_t*)(P1 + s1);
                a00 += bf2f((ushort_t)(v00 & 0xffff)) + bf2f((ushort_t)(v01 & 0xffff));
                a01 += bf2f((ushort_t)(v00 >> 16))    + bf2f((ushort_t)(v01 >> 16));
                a10 += bf2f((ushort_t)(v10 & 0xffff)) + bf2f((ushort_t)(v11 & 0xffff));
                a11 += bf2f((ushort_t)(v10 >> 16))    + bf2f((ushort_t)(v11 >> 16));
            }
            if (p < p1) {
                long s = (long)srcs[p] * W;
                uint_t v0 = *(const uint_t*)(P0 + s);
                uint_t v1 = *(const uint_t*)(P1 + s);
                a00 += bf2f((ushort_t)(v0 & 0xffff)); a01 += bf2f((ushort_t)(v0 >> 16));
                a10 += bf2f((ushort_t)(v1 & 0xffff)); a11 += bf2f((ushort_t)(v1 >> 16));
            }
        } else {
            int p = p0;
            for (; p + 7 < p1; p += 8) {
                uint_t v0 = *(const uint_t*)(P0 + (long)srcs[p] * W);
                uint_t v1 = *(const uint_t*)(P0 + (long)srcs[p + 1] * W);
                uint_t v2 = *(const uint_t*)(P0 + (long)srcs[p + 2] * W);
                uint_t v3 = *(const uint_t*)(P0 + (long)srcs[p + 3] * W);
                uint_t v4 = *(const uint_t*)(P0 + (long)srcs[p + 4] * W);
                uint_t v5 = *(const uint_t*)(P0 + (long)srcs[p + 5] * W);
                uint_t v6 = *(const uint_t*)(P0 + (long)srcs[p + 6] * W);
                uint_t v7 = *(const uint_t*)(P0 + (long)srcs[p + 7] * W);
                a00 += bf2f((ushort_t)(v0 & 0xffff)) + bf2f((ushort_t)(v1 & 0xffff))
                     + bf2f((ushort_t)(v2 & 0xffff)) + bf2f((ushort_t)(v3 & 0xffff));
                a01 += bf2f((ushort_t)(v0 >> 16)) + bf2f((ushort_t)(v1 >> 16))
                     + bf2f((ushort_t)(v2 >> 16)) + bf2f((ushort_t)(v3 >> 16));
                a00 += bf2f((ushort_t)(v4 & 0xffff)) + bf2f((ushort_t)(v5 & 0xffff))
                     + bf2f((ushort_t)(v6 & 0xffff)) + bf2f((ushort_t)(v7 & 0xffff));
                a01 += bf2f((ushort_t)(v4 >> 16)) + bf2f((ushort_t)(v5 >> 16))
                     + bf2f((ushort_t)(v6 >> 16)) + bf2f((ushort_t)(v7 >> 16));
            }
            for (; p + 3 < p1; p += 4) {
                uint_t v0 = *(const uint_t*)(P0 + (long)srcs[p] * W);
                uint_t v1 = *(const uint_t*)(P0 + (long)srcs[p + 1] * W);
                uint_t v2 = *(const uint_t*)(P0 + (long)srcs[p + 2] * W);
                uint_t v3 = *(const uint_t*)(P0 + (long)srcs[p + 3] * W);
                a00 += bf2f((ushort_t)(v0 & 0xffff)) + bf2f((ushort_t)(v1 & 0xffff))
                     + bf2f((ushort_t)(v2 & 0xffff)) + bf2f((ushort_t)(v3 & 0xffff));
                a01 += bf2f((ushort_t)(v0 >> 16)) + bf2f((ushort_t)(v1 >> 16))
                     + bf2f((ushort_t)(v2 >> 16)) + bf2f((ushort_t)(v3 >> 16));
            }
            for (; p < p1; ++p) {
                uint_t v = *(const uint_t*)(P0 + (long)srcs[p] * W);
                a00 += bf2f((ushort_t)(v & 0xffff)); a01 += bf2f((ushort_t)(v >> 16));
            }
        }
        {
            int e = e0 + zs[0];
            uint_t rv = *(const uint_t*)(PR + (long)n * W + zs[0] * 256 + 128 + c0);
            o0 += wv[0] * (a00 + bf2f((ushort_t)(rv & 0xffff)) + b2[e * O_DIM + c0]);
            o1 += wv[0] * (a01 + bf2f((ushort_t)(rv >> 16))    + b2[e * O_DIM + c0 + 1]);
        }
        if (na == 2) {
            int e = e0 + zs[1];
            uint_t rv = *(const uint_t*)(PR + (long)n * W + zs[1] * 256 + 128 + c0);
            o0 += wv[1] * (a10 + bf2f((ushort_t)(rv & 0xffff)) + b2[e * O_DIM + c0]);
            o1 += wv[1] * (a11 + bf2f((ushort_t)(rv >> 16))    + b2[e * O_DIM + c0 + 1]);
        }
    }
    out[obase] = o0;
    out[obase + 1] = o1;
}

// ==================== host launcher ====================
extern "C" void kernel_launch(void* const* d_in, const int* in_sizes, int n_in,
                              void* d_out, int out_size, void* d_ws, size_t ws_size,
                              hipStream_t stream) {
    const float* x       = (const float*)d_in[0];
    const int*   ei      = (const int*)  d_in[1];
    const int*   batch   = (const int*)  d_in[2];
    const float* enc_W1  = (const float*)d_in[3];
    const float* enc_b1  = (const float*)d_in[4];
    const float* enc_W2  = (const float*)d_in[5];
    const float* enc_b2  = (const float*)d_in[6];
    const float* r_W1    = (const float*)d_in[7];
    const float* r_b1    = (const float*)d_in[8];
    const float* ln_g    = (const float*)d_in[9];
    const float* ln_b    = (const float*)d_in[10];
    const float* r_W2    = (const float*)d_in[11];
    const float* r_b2    = (const float*)d_in[12];
    const float* centers = (const float*)d_in[13];
    const float* W0_rel  = (const float*)d_in[14];
    const float* b0_rel  = (const float*)d_in[15];
    const float* W0_root = (const float*)d_in[16];
    const float* W1_rel  = (const float*)d_in[17];
    const float* b1_rel  = (const float*)d_in[18];
    const float* W1_root = (const float*)d_in[19];
    const float* W2_rel  = (const float*)d_in[20];
    const float* b2_rel  = (const float*)d_in[21];
    const float* W2_root = (const float*)d_in[22];

    const int N = in_sizes[2];
    const int E = in_sizes[1] / 2;
    const int F = in_sizes[0] / N;

    // ---- workspace layout (256B-aligned slabs) ----
    char* ws = (char*)d_ws;
    size_t off = 0;
    auto alloc = [&](size_t bytes) -> void* {
        void* p = ws + off;
        off += (bytes + 255) & ~(size_t)255;
        return p;
    };
    int* cnt      = (int*)alloc((size_t)N * 4);
    int* fillc    = (int*)alloc((size_t)N * 4);
    int* gn       = (int*)alloc((size_t)G_DIM * 4);
    int* ge       = (int*)alloc((size_t)G_DIM * 4);
    size_t zero_bytes = off;
    int* row_ptr  = (int*)alloc((size_t)(N + 1) * 4);
    int* srcs     = (int*)alloc((size_t)E * 4);
    float* feats_norm = (float*)alloc((size_t)G_DIM * 3 * 4);
    float* logn_norm  = (float*)alloc((size_t)G_DIM * 4);
    float* wts    = (float*)alloc((size_t)N * NEXP * 4);
    // fused bf16 weights
    ushort_t* wf0  = (ushort_t*)alloc((size_t)NEXP * 131072 * 2);
    ushort_t* wf1  = (ushort_t*)alloc((size_t)NEXP * 131072 * 2);
    ushort_t* wfin = (ushort_t*)alloc((size_t)NEXP * 65536 * 2);

    const long sE = (long)N * H_DIM;               // elements per expert slab
    size_t fixed_end = off;
    size_t slab4 = ((size_t)4 * sE * 2 + 255) & ~(size_t)255;
    size_t slab2 = ((size_t)2 * sE * 2 + 255) & ~(size_t)255;
    size_t need4 = fixed_end + 3 * slab4 + (1u << 20);

    int EB;
    ushort_t *S1, *S2, *S3, *h_bf, *aggh_bf;
    float *u, *h, *tf32;
    if (ws_size >= need4) {
        // EB=4 overlay layout: h_bf/aggh_bf/t packed into S3 (die before hE1 write)
        EB = 4;
        S1 = (ushort_t*)alloc(slab4);   // u(fp32, first half) -> hE0 -> PR
        S2 = (ushort_t*)alloc(slab4);   // h(fp32, first half) -> aggE
        S3 = (ushort_t*)alloc(slab4);   // [h_bf | aggh_bf | t(fp32)] -> hE1
        u = (float*)S1; h = (float*)S2;
        h_bf = S3; aggh_bf = S3 + sE;
        tf32 = (float*)(S3 + 2 * sE);   // 51.2 MB, second half of S3
    } else {
        // EB=2 fallback (proven R10 footprint)
        EB = 2;
        h_bf    = (ushort_t*)alloc((size_t)sE * 2);
        aggh_bf = (ushort_t*)alloc((size_t)sE * 2);
        S1 = (ushort_t*)alloc(slab2);
        S2 = (ushort_t*)alloc(slab2);
        S3 = (ushort_t*)alloc(slab2);
        u = (float*)S1; h = (float*)S2; tf32 = (float*)S3;
    }
    (void)out_size; (void)n_in;

    ushort_t* hE0  = S1;
    ushort_t* aggE = S2;
    ushort_t* hE1  = S3;
    ushort_t* PR   = S1;                 // hE0 dead after GEMM1
    float* out = (float*)d_out;

    const int W  = EB * 256;             // interleaved row width (elements)
    dim3 blk256(256);
    dim3 gR((N + 63) / 64, H_DIM / 64, 1);   // fp32 SGEMM grid (router path)
    dim3 gM((N + 63) / 64, 2, EB);           // MFMA grid, 64-row tiles
    dim3 gAgg((N + 3) / 4);

    // 0) zero counters
    {
        long nz = (long)(zero_bytes / 4);
        zero_i_kernel<<<dim3((nz + 255) / 256), blk256, 0, stream>>>((int*)ws, nz);
    }
    // 0b) fused weight prep (single bf16)
    wsplit2_kernel<<<dim3(512, NEXP), blk256, 0, stream>>>(W0_rel, W0_root, wf0);
    wsplit2_kernel<<<dim3(512, NEXP), blk256, 0, stream>>>(W1_rel, W1_root, wf1);
    wsplitcat_kernel<<<dim3(256, NEXP), blk256, 0, stream>>>(W2_rel, W2_root, wfin);
    // 1) encoder stage 1 -> u
    encoder1_kernel<<<dim3(N), blk256, 0, stream>>>(x, enc_W1, enc_b1, u, N, F);
    // 2) h = u @ enc_W2 + enc_b2 (fp32 SGEMM + bf16 shadow)
    gemm256_kernel<<<gR, blk256, 0, stream>>>(u, enc_W2, enc_b2, h, h_bf, N, H_DIM);
    // 3-5) graph stats
    hist_nodes_kernel<<<dim3(256), blk256, 0, stream>>>(batch, N, gn);
    hist_edges_kernel<<<dim3(512), blk256, 0, stream>>>(ei, batch, E, ge);
    graph_stats_kernel<<<dim3(1), dim3(64), 0, stream>>>(gn, ge, feats_norm, logn_norm);
    // 6) t = h @ r_W1[0:256,:] (fp32 SGEMM)
    gemm256_kernel<<<gR, blk256, 0, stream>>>(h, r_W1, nullptr, tf32, nullptr, N, H_DIM);
    // 7) router epilogue -> wts
    router_epi_kernel<<<dim3((N + 3) / 4), blk256, 0, stream>>>(
        tf32, batch, feats_norm, logn_norm, r_W1, r_b1, ln_g, ln_b, r_W2, r_b2, centers, wts, N);
    // 8-10) CSR build
    count_dst_kernel<<<dim3((E + 255) / 256), blk256, 0, stream>>>(ei, E, cnt);
    scan_kernel<<<dim3(1), dim3(1024), 0, stream>>>(cnt, row_ptr, N);
    fill_csr_kernel<<<dim3((E + 255) / 256), blk256, 0, stream>>>(ei, E, row_ptr, fillc, srcs);
    // 11) agg_h = Agg(h_bf)  (flat gather)
    agg_b2b_kernel<<<gAgg, blk256, 0, stream>>>(h_bf, aggh_bf, row_ptr, srcs, N);

    // ---- expert pipeline, EB experts per dispatch, interleaved [n][z][h] slabs ----
    for (int b = 0; b < NEXP / EB; ++b) {
        const int e0 = b * EB;
        // hE0[n][z] = relu([agg_h | h] @ [W0_rel;W0_root]^T + b0)   (A shared across z)
        gemm_bf_kernel<2><<<gM, blk256, 0, stream>>>(
            aggh_bf, 0, 256, h_bf, 0, 256,
            wf0 + (long)e0 * 131072, 131072,
            b0_rel + e0 * H_DIM, H_DIM, hE0, 256, W, N, 512, 1);
        // aggE[n][z] = Agg(hE0)
        aggI_kernel<<<dim3(N), dim3(W / 8), 0, stream>>>(hE0, aggE, row_ptr, srcs, N, W);
        // hE1[n][z] = relu([aggE | hE0] @ [W1_rel;W1_root]^T + b1)
        gemm_bf_kernel<2><<<gM, blk256, 0, stream>>>(
            aggE, 256, W, hE0, 256, W,
            wf1 + (long)e0 * 131072, 131072,
            b1_rel + e0 * H_DIM, H_DIM, hE1, 256, W, N, 512, 1);
        // PR[n][z] = hE1 @ [W2_rel|W2_root]^T   (overlay onto dead hE0/S1)
        gemm_bf_kernel<1><<<gM, blk256, 0, stream>>>(
            hE1, 256, W, nullptr, 0, 256,
            wfin + (long)e0 * 65536, 65536,
            nullptr, 0, PR, 256, W, N, 256, 0);
        // out (+)= sum_z w[:,e0+z] * (Agg(P[z]) + R[z] + b2[e0+z])
        final_mixE_kernel<<<gAgg, blk256, 0, stream>>>(
            PR, b2_rel, wts, e0, EB, row_ptr, srcs, out, N, b == 0 ? 1 : 0);
    }
}

// Round 2
// 1238.778 us; speedup vs baseline: 1.0109x; 1.0010x over previous
//
#include <hip/hip_runtime.h>
#include <hip/hip_bf16.h>

// ---------------- problem constants ----------------
#define H_DIM 256
#define O_DIM 128
#define NEXP 4
#define G_DIM 64

typedef unsigned short ushort_t;
typedef unsigned int uint_t;
typedef __attribute__((ext_vector_type(8))) short short8;
typedef __attribute__((ext_vector_type(4))) float floatx4;

// ---------------- bf16 helpers (RNE) ----------------
__device__ __forceinline__ float bf2f(ushort_t u) {
    union { uint_t i; float f; } c; c.i = ((uint_t)u) << 16; return c.f;
}
__device__ __forceinline__ ushort_t f2bf(float f) {
    union { float f; uint_t i; } c; c.f = f;
    uint_t x = c.i;
    uint_t r = (x + 0x7fffu + ((x >> 16) & 1u)) >> 16;
    return (ushort_t)r;
}

// ---------------- XCD-aware bijective block swizzle (T1, m204 variant) ----------------
// Round-robin dispatch sends bid%8 to XCD (bid%8). Remap so each XCD owns a
// CONTIGUOUS node chunk: graphs (contiguous node ids, batch sorted) stay hot in
// one XCD's private 4MB L2 instead of being re-fetched by all 8.
__device__ __forceinline__ int xcd_swz(int bid, int nwg) {
    int q = nwg >> 3, r = nwg & 7;
    int x = bid & 7, i = bid >> 3;
    int base = (x < r) ? x * (q + 1) : r * (q + 1) + (x - r) * q;
    return base + i;
}

// ---------------- async global->LDS 16B ----------------
__device__ __forceinline__ void load16_lds(const void* g, void* l) {
    __builtin_amdgcn_global_load_lds(
        (const __attribute__((address_space(1))) unsigned int*)g,
        (__attribute__((address_space(3))) unsigned int*)l, 16, 0, 0);
}

// ---------------- utility: zero ints ----------------
__global__ void zero_i_kernel(int* __restrict__ p, long n) {
    long i = (long)blockIdx.x * blockDim.x + threadIdx.x;
    if (i < n) p[i] = 0;
}

// ---------------- fused weight prep (single bf16, transposed) ----------------
__global__ void wsplit2_kernel(const float* __restrict__ Wa, const float* __restrict__ Wb,
                               ushort_t* __restrict__ Wh) {
    int z = blockIdx.y;
    int i = blockIdx.x * 256 + threadIdx.x;        // 256n * 512k
    if (i >= 131072) return;
    int nn = i >> 9, kk = i & 511;
    float v = (kk < 256) ? Wa[(long)z * 65536 + kk * 256 + nn]
                         : Wb[(long)z * 65536 + (kk - 256) * 256 + nn];
    Wh[(long)z * 131072 + i] = f2bf(v);
}

__global__ void wsplitcat_kernel(const float* __restrict__ Wa, const float* __restrict__ Wb,
                                 ushort_t* __restrict__ Wh) {
    int z = blockIdx.y;
    int i = blockIdx.x * 256 + threadIdx.x;        // 256n * 256k
    if (i >= 65536) return;
    int nn = i >> 8, kk = i & 255;
    float v = (nn < 128) ? Wa[(long)z * 32768 + kk * 128 + nn]
                         : Wb[(long)z * 32768 + kk * 128 + (nn - 128)];
    Wh[(long)z * 65536 + i] = f2bf(v);
}

// ---------------- encoder stage 1 (fp32, verified) ----------------
__global__ void encoder1_kernel(const float* __restrict__ x, const float* __restrict__ W1,
                                const float* __restrict__ b1, float* __restrict__ u,
                                int N, int F) {
    int n = blockIdx.x;
    int j = threadIdx.x;
    float acc = b1[j];
    #pragma unroll
    for (int c = 0; c < 6; ++c)
        acc += x[(long)n * F + 4 + c] * W1[c * H_DIM + j];
    u[(long)n * H_DIM + j] = fmaxf(acc, 0.f);
}

// ---------------- fp32 vector SGEMM (router path — DO NOT CHANGE: top-2 flip risk) ----------------
__global__ __launch_bounds__(256)
void gemm256_kernel(const float* __restrict__ A, const float* __restrict__ W,
                    const float* __restrict__ bias, float* __restrict__ C,
                    ushort_t* __restrict__ Cbf, int M, int Nc) {
    const int K = 256;
    __shared__ float As[16][68];
    __shared__ float Ws[16][68];
    int tid = threadIdx.x;
    int tx = tid & 15, ty = tid >> 4;
    int row0 = blockIdx.x * 64;
    int col0 = blockIdx.y * 64;
    float acc[4][4] = {};
    int lrow = tid >> 2, kq = tid & 3;
    int wk = tid >> 4, wc = (tid & 15) * 4;
    for (int k0 = 0; k0 < K; k0 += 16) {
        float4 av = make_float4(0.f, 0.f, 0.f, 0.f);
        int arow = row0 + lrow;
        if (arow < M) av = *(const float4*)(A + (long)arow * K + k0 + kq * 4);
        As[kq * 4 + 0][lrow] = av.x;
        As[kq * 4 + 1][lrow] = av.y;
        As[kq * 4 + 2][lrow] = av.z;
        As[kq * 4 + 3][lrow] = av.w;
        float4 wv = *(const float4*)(W + (long)(k0 + wk) * Nc + col0 + wc);
        *(float4*)&Ws[wk][wc] = wv;
        __syncthreads();
        #pragma unroll
        for (int kk = 0; kk < 16; ++kk) {
            float a[4], b[4];
            #pragma unroll
            for (int i = 0; i < 4; ++i) a[i] = As[kk][ty * 4 + i];
            #pragma unroll
            for (int j = 0; j < 4; ++j) b[j] = Ws[kk][tx * 4 + j];
            #pragma unroll
            for (int i = 0; i < 4; ++i)
                #pragma unroll
                for (int j = 0; j < 4; ++j) acc[i][j] += a[i] * b[j];
        }
        __syncthreads();
    }
    #pragma unroll
    for (int i = 0; i < 4; ++i) {
        int r = row0 + ty * 4 + i;
        if (r >= M) break;
        #pragma unroll
        for (int j = 0; j < 4; ++j) {
            int c = col0 + tx * 4 + j;
            float v = acc[i][j];
            if (bias) v += bias[c];
            C[(long)r * Nc + c] = v;
            if (Cbf) Cbf[(long)r * Nc + c] = f2bf(v);
        }
    }
}

// ---------------- bf16 MFMA GEMM, 64x128 tile, double-buffered, z-batched ----------------
// C[z] = [relu]( sum_halves A_half[z](bf16) @ B[z]^T + [bias[z]] ); B fused (Nc=256, Kb) bf16.
// 64x128 tile, BK=32, 4 waves (2x2, wave tile 32x64), 2x4 frags of 16x16x32.
// LDS 24 KB -> ~6 resident blocks/CU; grid 2x vs 128-tile -> latency hidden by TLP.
// Add-rotate LDS swizzle (modulo-4 algebra verified R6-R10).
template<int NH>
__global__ __launch_bounds__(256)
void gemm_bf_kernel(const ushort_t* __restrict__ A1, long sA1z, int rsA1,
                    const ushort_t* __restrict__ A2, long sA2z, int rsA2,
                    const ushort_t* __restrict__ B, long sBz,
                    const float* __restrict__ bias, int sBiasz,
                    ushort_t* __restrict__ Cbf, long sCz, int rsC,
                    int M, int Kb, int relu) {
    __shared__ alignas(16) ushort_t Asl[2][64 * 32];
    __shared__ alignas(16) ushort_t Bsl[2][128 * 32];

    const int tid = threadIdx.x, wave = tid >> 6, lane = tid & 63;
    const int z = blockIdx.z;
    const int row0 = blockIdx.x * 64, col0 = blockIdx.y * 128;
    const int wr = (wave >> 1) * 32, wcx = (wave & 1) * 64;
    floatx4 acc[2][4] = {};

    A1 += (long)z * sA1z;
    A2 += (long)z * sA2z;
    B += (long)z * sBz;
    if (bias) bias += (long)z * sBiasz;
    Cbf += (long)z * sCz;

    // staging map: 4 lanes/row (4x16B chunks), add-rotate swizzle
    const int bsr = lane >> 2;                    // row in group of 16
    const int bgc = ((lane & 3) - (bsr >> 1)) & 3;
    long aoff1, aoff2;
    {
        int ar = row0 + wave * 16 + bsr;          // A: 16 rows per wave
        ar = ar < M ? ar : M - 1;
        aoff1 = (long)ar * rsA1 + bgc * 8;
        aoff2 = (long)ar * rsA2 + bgc * 8;
    }
    const long brow = (long)(col0 + wave * 32 + bsr) * Kb + bgc * 8;
    const ushort_t* Bg0 = B + brow;
    const ushort_t* Bg1 = B + brow + (long)16 * Kb;
    const int laA  = (wave * 16) * 32;
    const int laB0 = (wave * 32) * 32;
    const int laB1 = (wave * 32 + 16) * 32;

    const int fm = lane & 15, fq = lane >> 4;
    const int NK = NH * 8;

    // stage k=0 into buffer 0
    load16_lds(A1 + aoff1, &Asl[0][laA]);
    load16_lds(Bg0, &Bsl[0][laB0]);
    load16_lds(Bg1, &Bsl[0][laB1]);
    __syncthreads();

    for (int k = 0; k < NK; ++k) {
        const int buf = k & 1;
        short8 a[2], b[4];
        #pragma unroll
        for (int j = 0; j < 4; ++j) {
            int row = wcx + j * 16 + fm;
            int slot = (fq + ((row >> 1) & 3)) & 3;
            b[j] = *(const short8*)&Bsl[buf][row * 32 + slot * 8];
        }
        #pragma unroll
        for (int i = 0; i < 2; ++i) {
            int row = wr + i * 16 + fm;
            int slot = (fq + ((row >> 1) & 3)) & 3;
            a[i] = *(const short8*)&Asl[buf][row * 32 + slot * 8];
        }
        if (k + 1 < NK) {
            const int kn = k + 1, bn = kn & 1;
            const ushort_t* Ab = (kn >> 3) ? A2 : A1;
            const long ao = (kn >> 3) ? aoff2 : aoff1;
            const int k0 = (kn & 7) * 32;          // within-half A offset
            const int kk = kn * 32;                // fused-K B offset
            load16_lds(Ab + ao + k0, &Asl[bn][laA]);
            load16_lds(Bg0 + kk, &Bsl[bn][laB0]);
            load16_lds(Bg1 + kk, &Bsl[bn][laB1]);
        }
        #pragma unroll
        for (int i = 0; i < 2; ++i)
            #pragma unroll
            for (int j = 0; j < 4; ++j)
                acc[i][j] = __builtin_amdgcn_mfma_f32_16x16x32_bf16(a[i], b[j], acc[i][j], 0, 0, 0);
        if (k + 1 < NK) __syncthreads();
    }

    // epilogue: C/D layout col=lane&15, row=(lane>>4)*4+reg  [verified m89]
    #pragma unroll
    for (int i = 0; i < 2; ++i) {
        #pragma unroll
        for (int j = 0; j < 4; ++j) {
            int col = col0 + wcx + j * 16 + fm;
            int rowb = row0 + wr + i * 16 + fq * 4;
            #pragma unroll
            for (int r = 0; r < 4; ++r) {
                int row = rowb + r;
                if (row < M) {
                    float v = acc[i][j][r];
                    if (bias) v += bias[col];
                    if (relu) v = fmaxf(v, 0.f);
                    Cbf[(long)row * rsC + col] = f2bf(v);
                }
            }
        }
    }
}

// ---------------- graph-stat histograms ----------------
__global__ void hist_nodes_kernel(const int* __restrict__ batch, int n, int* __restrict__ gn) {
    __shared__ int bins[G_DIM];
    int t = threadIdx.x;
    if (t < G_DIM) bins[t] = 0;
    __syncthreads();
    for (long i = (long)blockIdx.x * blockDim.x + t; i < n; i += (long)gridDim.x * blockDim.x)
        atomicAdd(&bins[batch[i]], 1);
    __syncthreads();
    if (t < G_DIM) atomicAdd(&gn[t], bins[t]);
}

__global__ void hist_edges_kernel(const int* __restrict__ ei, const int* __restrict__ batch,
                                  int E, int* __restrict__ ge) {
    __shared__ int bins[G_DIM];
    int t = threadIdx.x;
    if (t < G_DIM) bins[t] = 0;
    __syncthreads();
    for (long i = (long)blockIdx.x * blockDim.x + t; i < E; i += (long)gridDim.x * blockDim.x)
        atomicAdd(&bins[batch[ei[i]]], 1);
    __syncthreads();
    if (t < G_DIM) atomicAdd(&ge[t], bins[t]);
}

// ---------------- graph stats ----------------
__global__ void graph_stats_kernel(const int* __restrict__ gn, const int* __restrict__ ge,
                                   float* __restrict__ feats_norm, float* __restrict__ logn_norm) {
    int g = threadIdx.x;
    float nv = fmaxf((float)gn[g], 1.0f);
    float ev = (float)ge[g];
    float density = ev / fmaxf(nv * (nv - 1.0f), 1.0f);
    float logn = logf(nv);
    float mn = logn, mx = logn;
    for (int o = 32; o; o >>= 1) {
        mn = fminf(mn, __shfl_xor(mn, o));
        mx = fmaxf(mx, __shfl_xor(mx, o));
    }
    logn_norm[g] = (logn - mn) / (mx - mn + 1e-6f);
    float f[3] = {nv, ev, density};
    #pragma unroll
    for (int c = 0; c < 3; ++c) {
        float s = f[c];
        for (int o = 32; o; o >>= 1) s += __shfl_xor(s, o);
        float mean = s / 64.f;
        float d = f[c] - mean;
        float v = d * d;
        for (int o = 32; o; o >>= 1) v += __shfl_xor(v, o);
        float stdv = sqrtf(v / 64.f);
        feats_norm[g * 3 + c] = d / (stdv + 1e-6f);
    }
}

// ---------------- router epilogue (verified) ----------------
__global__ __launch_bounds__(256)
void router_epi_kernel(const float* __restrict__ t, const int* __restrict__ batch,
                       const float* __restrict__ feats_norm, const float* __restrict__ logn_norm,
                       const float* __restrict__ rW1, const float* __restrict__ rb1,
                       const float* __restrict__ lng, const float* __restrict__ lnb,
                       const float* __restrict__ rW2, const float* __restrict__ rb2,
                       const float* __restrict__ centers, float* __restrict__ w, int N) {
    int wave = threadIdx.x >> 6, lane = threadIdx.x & 63;
    int n = blockIdx.x * 4 + wave;
    if (n >= N) return;
    int g = batch[n];
    float sf0 = feats_norm[g * 3 + 0], sf1 = feats_norm[g * 3 + 1], sf2 = feats_norm[g * 3 + 2];
    float ln = logn_norm[g];
    float tv[4];
    #pragma unroll
    for (int q = 0; q < 4; ++q) {
        int j = lane + 64 * q;
        tv[q] = t[(long)n * H_DIM + j] + rb1[j]
              + sf0 * rW1[256 * H_DIM + j] + sf1 * rW1[257 * H_DIM + j] + sf2 * rW1[258 * H_DIM + j];
    }
    float s = tv[0] + tv[1] + tv[2] + tv[3];
    for (int o = 32; o; o >>= 1) s += __shfl_xor(s, o);
    float mean = s / 256.f;
    float vs = 0.f;
    #pragma unroll
    for (int q = 0; q < 4; ++q) { float d = tv[q] - mean; vs += d * d; }
    for (int o = 32; o; o >>= 1) vs += __shfl_xor(vs, o);
    float rstd = rsqrtf(vs / 256.f + 1e-5f);
    float le[NEXP] = {0.f, 0.f, 0.f, 0.f};
    #pragma unroll
    for (int q = 0; q < 4; ++q) {
        int j = lane + 64 * q;
        float y = (tv[q] - mean) * rstd * lng[j] + lnb[j];
        y = fmaxf(y, 0.f);
        #pragma unroll
        for (int e = 0; e < NEXP; ++e) le[e] += y * rW2[j * NEXP + e];
    }
    #pragma unroll
    for (int e = 0; e < NEXP; ++e)
        for (int o = 32; o; o >>= 1) le[e] += __shfl_xor(le[e], o);
    if (lane == 0) {
        float p[NEXP];
        float m = -1e30f;
        #pragma unroll
        for (int e = 0; e < NEXP; ++e) {
            float d = ln - centers[e];
            float lv = 0.7f * (le[e] + rb2[e]) + 0.3f * (-(d * d));
            p[e] = lv;
            m = fmaxf(m, lv);
        }
        float ssum = 0.f;
        #pragma unroll
        for (int e = 0; e < NEXP; ++e) { p[e] = expf(p[e] - m); ssum += p[e]; }
        #pragma unroll
        for (int e = 0; e < NEXP; ++e) p[e] /= ssum;
        int i1 = 0;
        for (int e = 1; e < NEXP; ++e) if (p[e] > p[i1]) i1 = e;
        int i2 = -1;
        for (int e = 0; e < NEXP; ++e) { if (e == i1) continue; if (i2 < 0 || p[e] > p[i2]) i2 = e; }
        float denom = p[i1] + p[i2] + 1e-8f;
        float out4[NEXP] = {0.f, 0.f, 0.f, 0.f};
        out4[i1] = p[i1] / denom;
        out4[i2] = p[i2] / denom;
        #pragma unroll
        for (int e = 0; e < NEXP; ++e) w[(long)n * NEXP + e] = out4[e];
    }
}

// ---------------- CSR build ----------------
__global__ void count_dst_kernel(const int* __restrict__ ei, int E, int* __restrict__ cnt) {
    int i = blockIdx.x * blockDim.x + threadIdx.x;
    if (i < E) atomicAdd(&cnt[ei[E + i]], 1);
}

__global__ __launch_bounds__(1024)
void scan_kernel(const int* __restrict__ cnt, int* __restrict__ row_ptr, int n) {
    __shared__ int buf[1024];
    __shared__ int carry_s;
    int tid = threadIdx.x;
    if (tid == 0) carry_s = 0;
    __syncthreads();
    for (int base = 0; base < n; base += 1024) {
        int v = (base + tid < n) ? cnt[base + tid] : 0;
        buf[tid] = v;
        __syncthreads();
        for (int off = 1; off < 1024; off <<= 1) {
            int tv = (tid >= off) ? buf[tid - off] : 0;
            __syncthreads();
            buf[tid] += tv;
            __syncthreads();
        }
        int carry = carry_s;
        if (base + tid < n) row_ptr[base + tid] = carry + buf[tid] - v;
        __syncthreads();
        if (tid == 1023) carry_s = carry + buf[1023];
        __syncthreads();
    }
    if (tid == 0) row_ptr[n] = carry_s;
}

__global__ void fill_csr_kernel(const int* __restrict__ ei, int E, const int* __restrict__ row_ptr,
                                int* __restrict__ fillc, int* __restrict__ srcs) {
    int i = blockIdx.x * blockDim.x + threadIdx.x;
    if (i < E) {
        int d = ei[E + i];
        int pos = row_ptr[d] + atomicAdd(&fillc[d], 1);
        srcs[pos] = ei[i];
    }
}

// ---------------- flat CSR gather bf16 (agg_h), wave/node, edge-unrolled x4 (verified R9) ----------------
// + XCD-aware block swizzle: graph rows stay hot in one XCD's L2.
__global__ __launch_bounds__(256)
void agg_b2b_kernel(const ushort_t* __restrict__ feat, ushort_t* __restrict__ outp,
                    const int* __restrict__ rp, const int* __restrict__ srcs, int N) {
    int wave = threadIdx.x >> 6, lane = threadIdx.x & 63;
    int n = xcd_swz(blockIdx.x, gridDim.x) * 4 + wave;
    if (n >= N) return;
    float a0 = 0.f, a1 = 0.f, a2 = 0.f, a3 = 0.f;
    int p0 = rp[n], p1 = rp[n + 1];
    const ushort_t* base = feat + lane * 4;
    int p = p0;
    for (; p + 3 < p1; p += 4) {
        uint2 v0 = *(const uint2*)(base + (long)srcs[p] * H_DIM);
        uint2 v1 = *(const uint2*)(base + (long)srcs[p + 1] * H_DIM);
        uint2 v2 = *(const uint2*)(base + (long)srcs[p + 2] * H_DIM);
        uint2 v3 = *(const uint2*)(base + (long)srcs[p + 3] * H_DIM);
        a0 += bf2f((ushort_t)(v0.x & 0xffff)) + bf2f((ushort_t)(v1.x & 0xffff))
            + bf2f((ushort_t)(v2.x & 0xffff)) + bf2f((ushort_t)(v3.x & 0xffff));
        a1 += bf2f((ushort_t)(v0.x >> 16)) + bf2f((ushort_t)(v1.x >> 16))
            + bf2f((ushort_t)(v2.x >> 16)) + bf2f((ushort_t)(v3.x >> 16));
        a2 += bf2f((ushort_t)(v0.y & 0xffff)) + bf2f((ushort_t)(v1.y & 0xffff))
            + bf2f((ushort_t)(v2.y & 0xffff)) + bf2f((ushort_t)(v3.y & 0xffff));
        a3 += bf2f((ushort_t)(v0.y >> 16)) + bf2f((ushort_t)(v1.y >> 16))
            + bf2f((ushort_t)(v2.y >> 16)) + bf2f((ushort_t)(v3.y >> 16));
    }
    for (; p < p1; ++p) {
        uint2 v = *(const uint2*)(base + (long)srcs[p] * H_DIM);
        a0 += bf2f((ushort_t)(v.x & 0xffff));
        a1 += bf2f((ushort_t)(v.x >> 16));
        a2 += bf2f((ushort_t)(v.y & 0xffff));
        a3 += bf2f((ushort_t)(v.y >> 16));
    }
    uint2 o;
    o.x = (uint_t)f2bf(a0) | ((uint_t)f2bf(a1) << 16);
    o.y = (uint_t)f2bf(a2) | ((uint_t)f2bf(a3) << 16);
    *(uint2*)(outp + (long)n * H_DIM + lane * 4) = o;
}

// ---------------- interleaved CSR gather, 16B/lane: feat [n][W] bf16; block = W/8 threads ----------------
// + XCD-aware block swizzle (contiguous node chunk per XCD -> per-graph rows L2-resident).
__global__ void aggI_kernel(const ushort_t* __restrict__ feat, ushort_t* __restrict__ outp,
                            const int* __restrict__ rp, const int* __restrict__ srcs,
                            int N, int W) {
    int n = xcd_swz(blockIdx.x, N);
    int t = threadIdx.x;                      // t < W/8, 8 bf16 per thread
    float a[8] = {0.f, 0.f, 0.f, 0.f, 0.f, 0.f, 0.f, 0.f};
    int p0 = rp[n], p1 = rp[n + 1];
    const ushort_t* base = feat + t * 8;
    int p = p0;
    for (; p + 3 < p1; p += 4) {
        uint4 v0 = *(const uint4*)(base + (long)srcs[p] * W);
        uint4 v1 = *(const uint4*)(base + (long)srcs[p + 1] * W);
        uint4 v2 = *(const uint4*)(base + (long)srcs[p + 2] * W);
        uint4 v3 = *(const uint4*)(base + (long)srcs[p + 3] * W);
        uint_t w0[4] = {v0.x, v0.y, v0.z, v0.w};
        uint_t w1[4] = {v1.x, v1.y, v1.z, v1.w};
        uint_t w2[4] = {v2.x, v2.y, v2.z, v2.w};
        uint_t w3[4] = {v3.x, v3.y, v3.z, v3.w};
        #pragma unroll
        for (int q = 0; q < 4; ++q) {
            a[2 * q]     += bf2f((ushort_t)(w0[q] & 0xffff)) + bf2f((ushort_t)(w1[q] & 0xffff))
                          + bf2f((ushort_t)(w2[q] & 0xffff)) + bf2f((ushort_t)(w3[q] & 0xffff));
            a[2 * q + 1] += bf2f((ushort_t)(w0[q] >> 16)) + bf2f((ushort_t)(w1[q] >> 16))
                          + bf2f((ushort_t)(w2[q] >> 16)) + bf2f((ushort_t)(w3[q] >> 16));
        }
    }
    for (; p < p1; ++p) {
        uint4 v = *(const uint4*)(base + (long)srcs[p] * W);
        uint_t w[4] = {v.x, v.y, v.z, v.w};
        #pragma unroll
        for (int q = 0; q < 4; ++q) {
            a[2 * q]     += bf2f((ushort_t)(w[q] & 0xffff));
            a[2 * q + 1] += bf2f((ushort_t)(w[q] >> 16));
        }
    }
    uint4 o;
    o.x = (uint_t)f2bf(a[0]) | ((uint_t)f2bf(a[1]) << 16);
    o.y = (uint_t)f2bf(a[2]) | ((uint_t)f2bf(a[3]) << 16);
    o.z = (uint_t)f2bf(a[4]) | ((uint_t)f2bf(a[5]) << 16);
    o.w = (uint_t)f2bf(a[6]) | ((uint_t)f2bf(a[7]) << 16);
    *(uint4*)(outp + (long)n * W + t * 8) = o;
}

// ---------------- final mix on interleaved PR rows [n][z][256] (P cols 0..127, R 128..255) ----------------
// + XCD-aware block swizzle.
__global__ __launch_bounds__(256)
void final_mixE_kernel(const ushort_t* __restrict__ PR, const float* __restrict__ b2,
                       const float* __restrict__ wts, int e0, int EB,
                       const int* __restrict__ rp, const int* __restrict__ srcs,
                       float* __restrict__ out, int N, int init) {
    int wave = threadIdx.x >> 6, lane = threadIdx.x & 63;
    int n = xcd_swz(blockIdx.x, gridDim.x) * 4 + wave;
    if (n >= N) return;
    const int W = EB * 256;
    int c0 = lane * 2;
    long obase = (long)n * O_DIM + c0;
    float o0 = init ? 0.f : out[obase];
    float o1 = init ? 0.f : out[obase + 1];
    int zs[2]; float wv[2]; int na = 0;
    for (int z = 0; z < EB; ++z) {
        float w = wts[(long)n * NEXP + e0 + z];
        if (w != 0.f && na < 2) { zs[na] = z; wv[na] = w; ++na; }
    }
    if (na) {
        const ushort_t* P0 = PR + zs[0] * 256 + c0;
        const ushort_t* P1 = PR + zs[na - 1] * 256 + c0;
        float a00 = 0.f, a01 = 0.f, a10 = 0.f, a11 = 0.f;
        int p0 = rp[n], p1 = rp[n + 1];
        if (na == 2) {
            int p = p0;
            for (; p + 1 < p1; p += 2) {
                long s0 = (long)srcs[p] * W;
                long s1 = (long)srcs[p + 1] * W;
                uint_t v00 = *(const uint_t*)(P0 + s0);
                uint_t v10 = *(const uint_t*)(P1 + s0);
                uint_t v01 = *(const uint_t*)(P0 + s1);
                uint_t v11 = *(const uint_t*)(P1 + s1);
                a00 += bf2f((ushort_t)(v00 & 0xffff)) + bf2f((ushort_t)(v01 & 0xffff));
                a01 += bf2f((ushort_t)(v00 >> 16))    + bf2f((ushort_t)(v01 >> 16));
                a10 += bf2f((ushort_t)(v10 & 0xffff)) + bf2f((ushort_t)(v11 & 0xffff));
                a11 += bf2f((ushort_t)(v10 >> 16))    + bf2f((ushort_t)(v11 >> 16));
            }
            if (p < p1) {
                long s = (long)srcs[p] * W;
                uint_t v0 = *(const uint_t*)(P0 + s);
                uint_t v1 = *(const uint_t*)(P1 + s);
                a00 += bf2f((ushort_t)(v0 & 0xffff)); a01 += bf2f((ushort_t)(v0 >> 16));
                a10 += bf2f((ushort_t)(v1 & 0xffff)); a11 += bf2f((ushort_t)(v1 >> 16));
            }
        } else {
            int p = p0;
            for (; p + 3 < p1; p += 4) {
                uint_t v0 = *(const uint_t*)(P0 + (long)srcs[p] * W);
                uint_t v1 = *(const uint_t*)(P0 + (long)srcs[p + 1] * W);
                uint_t v2 = *(const uint_t*)(P0 + (long)srcs[p + 2] * W);
                uint_t v3 = *(const uint_t*)(P0 + (long)srcs[p + 3] * W);
                a00 += bf2f((ushort_t)(v0 & 0xffff)) + bf2f((ushort_t)(v1 & 0xffff))
                     + bf2f((ushort_t)(v2 & 0xffff)) + bf2f((ushort_t)(v3 & 0xffff));
                a01 += bf2f((ushort_t)(v0 >> 16)) + bf2f((ushort_t)(v1 >> 16))
                     + bf2f((ushort_t)(v2 >> 16)) + bf2f((ushort_t)(v3 >> 16));
            }
            for (; p < p1; ++p) {
                uint_t v = *(const uint_t*)(P0 + (long)srcs[p] * W);
                a00 += bf2f((ushort_t)(v & 0xffff)); a01 += bf2f((ushort_t)(v >> 16));
            }
        }
        {
            int e = e0 + zs[0];
            uint_t rv = *(const uint_t*)(PR + (long)n * W + zs[0] * 256 + 128 + c0);
            o0 += wv[0] * (a00 + bf2f((ushort_t)(rv & 0xffff)) + b2[e * O_DIM + c0]);
            o1 += wv[0] * (a01 + bf2f((ushort_t)(rv >> 16))    + b2[e * O_DIM + c0 + 1]);
        }
        if (na == 2) {
            int e = e0 + zs[1];
            uint_t rv = *(const uint_t*)(PR + (long)n * W + zs[1] * 256 + 128 + c0);
            o0 += wv[1] * (a10 + bf2f((ushort_t)(rv & 0xffff)) + b2[e * O_DIM + c0]);
            o1 += wv[1] * (a11 + bf2f((ushort_t)(rv >> 16))    + b2[e * O_DIM + c0 + 1]);
        }
    }
    out[obase] = o0;
    out[obase + 1] = o1;
}

// ==================== host launcher ====================
extern "C" void kernel_launch(void* const* d_in, const int* in_sizes, int n_in,
                              void* d_out, int out_size, void* d_ws, size_t ws_size,
                              hipStream_t stream) {
    const float* x       = (const float*)d_in[0];
    const int*   ei      = (const int*)  d_in[1];
    const int*   batch   = (const int*)  d_in[2];
    const float* enc_W1  = (const float*)d_in[3];
    const float* enc_b1  = (const float*)d_in[4];
    const float* enc_W2  = (const float*)d_in[5];
    const float* enc_b2  = (const float*)d_in[6];
    const float* r_W1    = (const float*)d_in[7];
    const float* r_b1    = (const float*)d_in[8];
    const float* ln_g    = (const float*)d_in[9];
    const float* ln_b    = (const float*)d_in[10];
    const float* r_W2    = (const float*)d_in[11];
    const float* r_b2    = (const float*)d_in[12];
    const float* centers = (const float*)d_in[13];
    const float* W0_rel  = (const float*)d_in[14];
    const float* b0_rel  = (const float*)d_in[15];
    const float* W0_root = (const float*)d_in[16];
    const float* W1_rel  = (const float*)d_in[17];
    const float* b1_rel  = (const float*)d_in[18];
    const float* W1_root = (const float*)d_in[19];
    const float* W2_rel  = (const float*)d_in[20];
    const float* b2_rel  = (const float*)d_in[21];
    const float* W2_root = (const float*)d_in[22];

    const int N = in_sizes[2];
    const int E = in_sizes[1] / 2;
    const int F = in_sizes[0] / N;

    // ---- workspace layout (256B-aligned slabs) ----
    char* ws = (char*)d_ws;
    size_t off = 0;
    auto alloc = [&](size_t bytes) -> void* {
        void* p = ws + off;
        off += (bytes + 255) & ~(size_t)255;
        return p;
    };
    int* cnt      = (int*)alloc((size_t)N * 4);
    int* fillc    = (int*)alloc((size_t)N * 4);
    int* gn       = (int*)alloc((size_t)G_DIM * 4);
    int* ge       = (int*)alloc((size_t)G_DIM * 4);
    size_t zero_bytes = off;
    int* row_ptr  = (int*)alloc((size_t)(N + 1) * 4);
    int* srcs     = (int*)alloc((size_t)E * 4);
    float* feats_norm = (float*)alloc((size_t)G_DIM * 3 * 4);
    float* logn_norm  = (float*)alloc((size_t)G_DIM * 4);
    float* wts    = (float*)alloc((size_t)N * NEXP * 4);
    // fused bf16 weights
    ushort_t* wf0  = (ushort_t*)alloc((size_t)NEXP * 131072 * 2);
    ushort_t* wf1  = (ushort_t*)alloc((size_t)NEXP * 131072 * 2);
    ushort_t* wfin = (ushort_t*)alloc((size_t)NEXP * 65536 * 2);

    const long sE = (long)N * H_DIM;               // elements per expert slab
    size_t fixed_end = off;
    size_t slab4 = ((size_t)4 * sE * 2 + 255) & ~(size_t)255;
    size_t slab2 = ((size_t)2 * sE * 2 + 255) & ~(size_t)255;
    size_t need4 = fixed_end + 3 * slab4 + (1u << 20);

    int EB;
    ushort_t *S1, *S2, *S3, *h_bf, *aggh_bf;
    float *u, *h, *tf32;
    if (ws_size >= need4) {
        // EB=4 overlay layout: h_bf/aggh_bf/t packed into S3 (die before hE1 write)
        EB = 4;
        S1 = (ushort_t*)alloc(slab4);   // u(fp32, first half) -> hE0 -> PR
        S2 = (ushort_t*)alloc(slab4);   // h(fp32, first half) -> aggE
        S3 = (ushort_t*)alloc(slab4);   // [h_bf | aggh_bf | t(fp32)] -> hE1
        u = (float*)S1; h = (float*)S2;
        h_bf = S3; aggh_bf = S3 + sE;
        tf32 = (float*)(S3 + 2 * sE);   // 51.2 MB, second half of S3
    } else {
        // EB=2 fallback (proven R10 footprint)
        EB = 2;
        h_bf    = (ushort_t*)alloc((size_t)sE * 2);
        aggh_bf = (ushort_t*)alloc((size_t)sE * 2);
        S1 = (ushort_t*)alloc(slab2);
        S2 = (ushort_t*)alloc(slab2);
        S3 = (ushort_t*)alloc(slab2);
        u = (float*)S1; h = (float*)S2; tf32 = (float*)S3;
    }
    (void)out_size; (void)n_in;

    ushort_t* hE0  = S1;
    ushort_t* aggE = S2;
    ushort_t* hE1  = S3;
    ushort_t* PR   = S1;                 // hE0 dead after GEMM1
    float* out = (float*)d_out;

    const int W  = EB * 256;             // interleaved row width (elements)
    dim3 blk256(256);
    dim3 gR((N + 63) / 64, H_DIM / 64, 1);   // fp32 SGEMM grid (router path)
    dim3 gM((N + 63) / 64, 2, EB);           // MFMA grid, 64-row tiles
    dim3 gAgg((N + 3) / 4);

    // 0) zero counters
    {
        long nz = (long)(zero_bytes / 4);
        zero_i_kernel<<<dim3((nz + 255) / 256), blk256, 0, stream>>>((int*)ws, nz);
    }
    // 0b) fused weight prep (single bf16)
    wsplit2_kernel<<<dim3(512, NEXP), blk256, 0, stream>>>(W0_rel, W0_root, wf0);
    wsplit2_kernel<<<dim3(512, NEXP), blk256, 0, stream>>>(W1_rel, W1_root, wf1);
    wsplitcat_kernel<<<dim3(256, NEXP), blk256, 0, stream>>>(W2_rel, W2_root, wfin);
    // 1) encoder stage 1 -> u
    encoder1_kernel<<<dim3(N), blk256, 0, stream>>>(x, enc_W1, enc_b1, u, N, F);
    // 2) h = u @ enc_W2 + enc_b2 (fp32 SGEMM + bf16 shadow)
    gemm256_kernel<<<gR, blk256, 0, stream>>>(u, enc_W2, enc_b2, h, h_bf, N, H_DIM);
    // 3-5) graph stats
    hist_nodes_kernel<<<dim3(256), blk256, 0, stream>>>(batch, N, gn);
    hist_edges_kernel<<<dim3(512), blk256, 0, stream>>>(ei, batch, E, ge);
    graph_stats_kernel<<<dim3(1), dim3(64), 0, stream>>>(gn, ge, feats_norm, logn_norm);
    // 6) t = h @ r_W1[0:256,:] (fp32 SGEMM)
    gemm256_kernel<<<gR, blk256, 0, stream>>>(h, r_W1, nullptr, tf32, nullptr, N, H_DIM);
    // 7) router epilogue -> wts
    router_epi_kernel<<<dim3((N + 3) / 4), blk256, 0, stream>>>(
        tf32, batch, feats_norm, logn_norm, r_W1, r_b1, ln_g, ln_b, r_W2, r_b2, centers, wts, N);
    // 8-10) CSR build
    count_dst_kernel<<<dim3((E + 255) / 256), blk256, 0, stream>>>(ei, E, cnt);
    scan_kernel<<<dim3(1), dim3(1024), 0, stream>>>(cnt, row_ptr, N);
    fill_csr_kernel<<<dim3((E + 255) / 256), blk256, 0, stream>>>(ei, E, row_ptr, fillc, srcs);
    // 11) agg_h = Agg(h_bf)  (flat gather)
    agg_b2b_kernel<<<gAgg, blk256, 0, stream>>>(h_bf, aggh_bf, row_ptr, srcs, N);

    // ---- expert pipeline, EB experts per dispatch, interleaved [n][z][h] slabs ----
    for (int b = 0; b < NEXP / EB; ++b) {
        const int e0 = b * EB;
        // hE0[n][z] = relu([agg_h | h] @ [W0_rel;W0_root]^T + b0)   (A shared across z)
        gemm_bf_kernel<2><<<gM, blk256, 0, stream>>>(
            aggh_bf, 0, 256, h_bf, 0, 256,
            wf0 + (long)e0 * 131072, 131072,
            b0_rel + e0 * H_DIM, H_DIM, hE0, 256, W, N, 512, 1);
        // aggE[n][z] = Agg(hE0)
        aggI_kernel<<<dim3(N), dim3(W / 8), 0, stream>>>(hE0, aggE, row_ptr, srcs, N, W);
        // hE1[n][z] = relu([aggE | hE0] @ [W1_rel;W1_root]^T + b1)
        gemm_bf_kernel<2><<<gM, blk256, 0, stream>>>(
            aggE, 256, W, hE0, 256, W,
            wf1 + (long)e0 * 131072, 131072,
            b1_rel + e0 * H_DIM, H_DIM, hE1, 256, W, N, 512, 1);
        // PR[n][z] = hE1 @ [W2_rel|W2_root]^T   (overlay onto dead hE0/S1)
        gemm_bf_kernel<1><<<gM, blk256, 0, stream>>>(
            hE1, 256, W, nullptr, 0, 256,
            wfin + (long)e0 * 65536, 65536,
            nullptr, 0, PR, 256, W, N, 256, 0);
        // out (+)= sum_z w[:,e0+z] * (Agg(P[z]) + R[z] + b2[e0+z])
        final_mixE_kernel<<<gAgg, blk256, 0, stream>>>(
            PR, b2_rel, wts, e0, EB, row_ptr, srcs, out, N, b == 0 ? 1 : 0);
    }
}